// Round 1
// baseline (399.898 us; speedup 1.0000x reference)
//
#include <hip/hip_runtime.h>
#include <hip/hip_bf16.h>
#include <math.h>

// Problem geometry
#define MTOT  16384      // B*L = 4*4096
#define DM    1024
#define HIDN  128
#define HNB   256        // H*NB
#define LLEN  4096
#define NBAT  4

// ---------------------------------------------------------------------------
// Kernel A: h = gelu(content @ W1 + b1)   [16384,1024]x[1024,128] fp32
// BM=64, BN=128, BK=32; 256 threads; micro-tile 4(M)x8(N) per thread.
// ---------------------------------------------------------------------------
__global__ __launch_bounds__(256) void k_gemm1_gelu(
    const float* __restrict__ A,    // content [16384,1024]
    const float* __restrict__ W1,   // [1024,128]
    const float* __restrict__ b1,   // [128]
    float* __restrict__ Hout)       // [16384,128]
{
    __shared__ float As[32][68];    // [k][m], padded
    __shared__ float Bs[32][140];   // [k][n], +4 pad per 32 cols (bank swizzle)

    const int tid = threadIdx.x;
    const int m0  = blockIdx.x * 64;
    const int ty  = tid >> 4;       // 0..15 -> rows ty*4..+3
    const int tx  = tid & 15;       // 0..15 -> cols tx*8..+7
    const int bc  = tx * 8 + ((tx >> 2) << 2);  // swizzled col base

    const int ar  = tid >> 2;       // 0..63  (A stage row)
    const int as  = tid & 3;        // A stage slot
    const int bkr = tid >> 3;       // 0..31  (B stage k-row)
    const int bcq = tid & 7;

    float acc[4][8];
    #pragma unroll
    for (int i = 0; i < 4; ++i)
        #pragma unroll
        for (int j = 0; j < 8; ++j) acc[i][j] = 0.0f;

    for (int kt = 0; kt < DM / 32; ++kt) {
        const int k0 = kt * 32;
        // stage A tile, transposed into [k][m]
        #pragma unroll
        for (int i = 0; i < 2; ++i) {
            int slot = as + i * 4;  // 0..7 (float4 slot within 32 k's)
            float4 v = *reinterpret_cast<const float4*>(
                &A[(size_t)(m0 + ar) * DM + k0 + slot * 4]);
            As[slot * 4 + 0][ar] = v.x;
            As[slot * 4 + 1][ar] = v.y;
            As[slot * 4 + 2][ar] = v.z;
            As[slot * 4 + 3][ar] = v.w;
        }
        // stage W1 tile [k][n]
        #pragma unroll
        for (int i = 0; i < 4; ++i) {
            int col = bcq * 4 + i * 32;
            float4 w = *reinterpret_cast<const float4*>(
                &W1[(size_t)(k0 + bkr) * HIDN + col]);
            int sc = col + ((col >> 5) << 2);
            *reinterpret_cast<float4*>(&Bs[bkr][sc]) = w;
        }
        __syncthreads();
        #pragma unroll
        for (int k = 0; k < 32; ++k) {
            float4 a  = *reinterpret_cast<const float4*>(&As[k][ty * 4]);
            float4 w0 = *reinterpret_cast<const float4*>(&Bs[k][bc]);
            float4 w1 = *reinterpret_cast<const float4*>(&Bs[k][bc + 4]);
            float av[4] = {a.x, a.y, a.z, a.w};
            float bv[8] = {w0.x, w0.y, w0.z, w0.w, w1.x, w1.y, w1.z, w1.w};
            #pragma unroll
            for (int i = 0; i < 4; ++i)
                #pragma unroll
                for (int j = 0; j < 8; ++j)
                    acc[i][j] = fmaf(av[i], bv[j], acc[i][j]);
        }
        __syncthreads();
    }

    // epilogue: bias + exact GELU, store h
    #pragma unroll
    for (int i = 0; i < 4; ++i) {
        int row = m0 + ty * 4 + i;
        #pragma unroll
        for (int j = 0; j < 8; ++j) {
            float y = acc[i][j] + b1[tx * 8 + j];
            acc[i][j] = 0.5f * y * (1.0f + erff(y * 0.70710678118654752f));
        }
        float4 s0 = {acc[i][0], acc[i][1], acc[i][2], acc[i][3]};
        float4 s1 = {acc[i][4], acc[i][5], acc[i][6], acc[i][7]};
        *reinterpret_cast<float4*>(&Hout[(size_t)row * HIDN + tx * 8])     = s0;
        *reinterpret_cast<float4*>(&Hout[(size_t)row * HIDN + tx * 8 + 4]) = s1;
    }
}

// ---------------------------------------------------------------------------
// Kernel B: y2 = h @ W2 + b2; z = pi*tanh(y2); nu = wrap(z - theta); u = K*nu
// Tile: 32 rows (l) x 256 channels; 256 threads; micro 4(l) x 8(hc).
// ---------------------------------------------------------------------------
__global__ __launch_bounds__(256) void k_gemm2_u(
    const float* __restrict__ Hin,    // [16384,128]
    const float* __restrict__ W2,     // [128,256]
    const float* __restrict__ b2,     // [256]
    const float* __restrict__ theta,  // [16384,256]
    const float* __restrict__ logPi,  // [256]
    const float* __restrict__ logR,   // [256]
    float* __restrict__ Ubuf)         // [16384,256]
{
    __shared__ float hs[32][132];     // [l][j]
    __shared__ float ws[32][288];     // [j][hc], +4 pad per 32 cols

    const int tid = threadIdx.x;
    const int m0  = blockIdx.x * 32;

    // stage h tile (all 128 j)
    {
        int r = tid >> 3, q = tid & 7;
        #pragma unroll
        for (int i = 0; i < 4; ++i) {
            int col = q * 4 + i * 32;
            float4 v = *reinterpret_cast<const float4*>(
                &Hin[(size_t)(m0 + r) * HIDN + col]);
            *reinterpret_cast<float4*>(&hs[r][col]) = v;
        }
    }

    const int ly = tid >> 5;   // 0..7  -> rows ly*4..+3
    const int cx = tid & 31;   // 0..31 -> cols cx*8..+7
    const int wc = cx * 8 + ((cx >> 2) << 2);

    float acc[4][8];
    #pragma unroll
    for (int i = 0; i < 4; ++i)
        #pragma unroll
        for (int c = 0; c < 8; ++c) acc[i][c] = 0.0f;

    const int jr = tid >> 3, cq = tid & 7;
    for (int jc = 0; jc < 4; ++jc) {
        __syncthreads();   // hs ready (1st iter) / ws consumed (later iters)
        #pragma unroll
        for (int i = 0; i < 8; ++i) {
            int col = cq * 4 + i * 32;
            float4 v = *reinterpret_cast<const float4*>(
                &W2[(size_t)(jc * 32 + jr) * HNB + col]);
            int sc = col + ((col >> 5) << 2);
            *reinterpret_cast<float4*>(&ws[jr][sc]) = v;
        }
        __syncthreads();
        #pragma unroll
        for (int j4 = 0; j4 < 8; ++j4) {
            float hvf[4][4];
            #pragma unroll
            for (int i = 0; i < 4; ++i) {
                float4 t = *reinterpret_cast<const float4*>(
                    &hs[ly * 4 + i][jc * 32 + j4 * 4]);
                hvf[i][0] = t.x; hvf[i][1] = t.y; hvf[i][2] = t.z; hvf[i][3] = t.w;
            }
            #pragma unroll
            for (int jj = 0; jj < 4; ++jj) {
                float4 w0 = *reinterpret_cast<const float4*>(&ws[j4 * 4 + jj][wc]);
                float4 w1 = *reinterpret_cast<const float4*>(&ws[j4 * 4 + jj][wc + 4]);
                float wv[8] = {w0.x, w0.y, w0.z, w0.w, w1.x, w1.y, w1.z, w1.w};
                #pragma unroll
                for (int i = 0; i < 4; ++i)
                    #pragma unroll
                    for (int c = 0; c < 8; ++c)
                        acc[i][c] = fmaf(hvf[i][jj], wv[c], acc[i][c]);
            }
        }
    }

    // per-thread channel constants
    float Kv[8], b2v[8];
    {
        float4 lp0 = *reinterpret_cast<const float4*>(&logPi[cx * 8]);
        float4 lp1 = *reinterpret_cast<const float4*>(&logPi[cx * 8 + 4]);
        float4 lr0 = *reinterpret_cast<const float4*>(&logR[cx * 8]);
        float4 lr1 = *reinterpret_cast<const float4*>(&logR[cx * 8 + 4]);
        float4 bb0 = *reinterpret_cast<const float4*>(&b2[cx * 8]);
        float4 bb1 = *reinterpret_cast<const float4*>(&b2[cx * 8 + 4]);
        float lpv[8] = {lp0.x, lp0.y, lp0.z, lp0.w, lp1.x, lp1.y, lp1.z, lp1.w};
        float lrv[8] = {lr0.x, lr0.y, lr0.z, lr0.w, lr1.x, lr1.y, lr1.z, lr1.w};
        float bbv[8] = {bb0.x, bb0.y, bb0.z, bb0.w, bb1.x, bb1.y, bb1.z, bb1.w};
        #pragma unroll
        for (int c = 0; c < 8; ++c) {
            float Pi = expf(lpv[c]);
            float R  = expf(lrv[c]);
            Kv[c]  = Pi / fmaxf(Pi + R, 1e-8f);
            b2v[c] = bbv[c];
        }
    }

    #pragma unroll
    for (int i = 0; i < 4; ++i) {
        int m = m0 + ly * 4 + i;
        float4 t0 = *reinterpret_cast<const float4*>(&theta[(size_t)m * HNB + cx * 8]);
        float4 t1 = *reinterpret_cast<const float4*>(&theta[(size_t)m * HNB + cx * 8 + 4]);
        float thv[8] = {t0.x, t0.y, t0.z, t0.w, t1.x, t1.y, t1.z, t1.w};
        float uv[8];
        #pragma unroll
        for (int c = 0; c < 8; ++c) {
            float y    = acc[i][c] + b2v[c];
            float z    = 3.14159265358979323846f * tanhf(y);
            float diff = z - thv[c];
            float kq   = rintf(diff * 0.15915494309189533577f);
            // wrapped residual; do the 2*pi*k subtraction in double to keep
            // the wrap decision aligned with the fp64 numpy reference
            float nu = (float)((double)diff - (double)kq * 6.283185307179586476925286766559);
            uv[c] = Kv[c] * nu;
        }
        float4 s0 = {uv[0], uv[1], uv[2], uv[3]};
        float4 s1 = {uv[4], uv[5], uv[6], uv[7]};
        *reinterpret_cast<float4*>(&Ubuf[(size_t)m * HNB + cx * 8])     = s0;
        *reinterpret_cast<float4*>(&Ubuf[(size_t)m * HNB + cx * 8 + 4]) = s1;
    }
}

// ---------------------------------------------------------------------------
// Kernel C: serial affine scan along L per channel; out0 = theta + d
// 1024 channels total: grid 4 (batch), block 256 (hc)
// ---------------------------------------------------------------------------
__global__ __launch_bounds__(256) void k_scan(
    const float* __restrict__ Ubuf,
    const float* __restrict__ theta,
    const float* __restrict__ logPi,
    const float* __restrict__ logR,
    float* __restrict__ out0)
{
    const int hc = threadIdx.x;
    const int b  = blockIdx.x;
    float Pi = expf(logPi[hc]);
    float R  = expf(logR[hc]);
    float K  = Pi / fmaxf(Pi + R, 1e-8f);
    float alpha = 1.0f - K;
    size_t base = (size_t)b * LLEN * HNB + hc;
    float d = 0.0f;
    #pragma unroll 8
    for (int l = 0; l < LLEN; ++l) {
        size_t idx = base + (size_t)l * HNB;
        float uu = Ubuf[idx];
        d = fmaf(alpha, d, uu);
        out0[idx] = theta[idx] + d;
    }
}

// ---------------------------------------------------------------------------
// Kernel D: broadcast-constant outputs 1..3 (Pi, K, R)
// one float4 per thread per region; grid 4096 x 256 covers 4,194,304 floats
// ---------------------------------------------------------------------------
__global__ __launch_bounds__(256) void k_fill(
    const float* __restrict__ logPi,
    const float* __restrict__ logR,
    float* __restrict__ out1,
    float* __restrict__ out2,
    float* __restrict__ out3)
{
    size_t s = (size_t)blockIdx.x * 256 + threadIdx.x;  // float4 slot
    int c0 = (int)((s & 63) << 2);                       // channel of elem 0
    float4 lp = *reinterpret_cast<const float4*>(&logPi[c0]);
    float4 lr = *reinterpret_cast<const float4*>(&logR[c0]);
    float4 Pi = {expf(lp.x), expf(lp.y), expf(lp.z), expf(lp.w)};
    float4 Rr = {expf(lr.x), expf(lr.y), expf(lr.z), expf(lr.w)};
    float4 Kk = {Pi.x / fmaxf(Pi.x + Rr.x, 1e-8f),
                 Pi.y / fmaxf(Pi.y + Rr.y, 1e-8f),
                 Pi.z / fmaxf(Pi.z + Rr.z, 1e-8f),
                 Pi.w / fmaxf(Pi.w + Rr.w, 1e-8f)};
    *reinterpret_cast<float4*>(&out1[s * 4]) = Pi;
    *reinterpret_cast<float4*>(&out2[s * 4]) = Kk;
    *reinterpret_cast<float4*>(&out3[s * 4]) = Rr;
}

extern "C" void kernel_launch(void* const* d_in, const int* in_sizes, int n_in,
                              void* d_out, int out_size, void* d_ws, size_t ws_size,
                              hipStream_t stream) {
    const float* theta   = (const float*)d_in[0];
    const float* content = (const float*)d_in[1];
    const float* W1      = (const float*)d_in[2];
    const float* b1      = (const float*)d_in[3];
    const float* W2      = (const float*)d_in[4];
    const float* b2      = (const float*)d_in[5];
    const float* logPi   = (const float*)d_in[6];
    const float* logR    = (const float*)d_in[7];

    float* out  = (float*)d_out;
    float* out0 = out;
    float* out1 = out + (size_t)MTOT * HNB;      // also h scratch (needs 2.1M floats)
    float* out2 = out + (size_t)2 * MTOT * HNB;  // also u scratch (4.19M floats)
    float* out3 = out + (size_t)3 * MTOT * HNB;

    float* Hbuf = out1;   // scratch in out1 region until k_fill overwrites it
    float* Ubuf = out2;   // scratch in out2 region until k_fill overwrites it

    hipLaunchKernelGGL(k_gemm1_gelu, dim3(MTOT / 64), dim3(256), 0, stream,
                       content, W1, b1, Hbuf);
    hipLaunchKernelGGL(k_gemm2_u, dim3(MTOT / 32), dim3(256), 0, stream,
                       Hbuf, W2, b2, theta, logPi, logR, Ubuf);
    hipLaunchKernelGGL(k_scan, dim3(NBAT), dim3(256), 0, stream,
                       Ubuf, theta, logPi, logR, out0);
    hipLaunchKernelGGL(k_fill, dim3((MTOT * HNB / 4) / 256), dim3(256), 0, stream,
                       logPi, logR, out1, out2, out3);
}

// Round 2
// 135.704 us; speedup vs baseline: 2.9468x; 2.9468x over previous
//
#include <hip/hip_runtime.h>
#include <hip/hip_bf16.h>
#include <math.h>

// Problem geometry
#define MTOT  16384      // B*L = 4*4096
#define DM    1024
#define HIDN  128
#define HNB   256        // H*NB
#define LLEN  4096
#define NBAT  4
#define CL    64         // scan chunk length
#define NCH   (LLEN/CL)  // 64 chunks per sequence

// ---------------------------------------------------------------------------
// Kernel A: h = gelu(content @ W1 + b1)   [16384,1024]x[1024,128] fp32
// BM=64, BN=128, BK=32; 256 threads; micro-tile 4(M)x8(N) per thread.
// ---------------------------------------------------------------------------
__global__ __launch_bounds__(256) void k_gemm1_gelu(
    const float* __restrict__ A,    // content [16384,1024]
    const float* __restrict__ W1,   // [1024,128]
    const float* __restrict__ b1,   // [128]
    float* __restrict__ Hout)       // [16384,128]
{
    __shared__ float As[32][68];    // [k][m], padded
    __shared__ float Bs[32][140];   // [k][n], +4 pad per 32 cols (bank swizzle)

    const int tid = threadIdx.x;
    const int m0  = blockIdx.x * 64;
    const int ty  = tid >> 4;       // 0..15 -> rows ty*4..+3
    const int tx  = tid & 15;       // 0..15 -> cols tx*8..+7
    const int bc  = tx * 8 + ((tx >> 2) << 2);  // swizzled col base

    const int ar  = tid >> 2;       // 0..63  (A stage row)
    const int as  = tid & 3;        // A stage slot
    const int bkr = tid >> 3;       // 0..31  (B stage k-row)
    const int bcq = tid & 7;

    float acc[4][8];
    #pragma unroll
    for (int i = 0; i < 4; ++i)
        #pragma unroll
        for (int j = 0; j < 8; ++j) acc[i][j] = 0.0f;

    for (int kt = 0; kt < DM / 32; ++kt) {
        const int k0 = kt * 32;
        // stage A tile, transposed into [k][m]
        #pragma unroll
        for (int i = 0; i < 2; ++i) {
            int slot = as + i * 4;  // 0..7 (float4 slot within 32 k's)
            float4 v = *reinterpret_cast<const float4*>(
                &A[(size_t)(m0 + ar) * DM + k0 + slot * 4]);
            As[slot * 4 + 0][ar] = v.x;
            As[slot * 4 + 1][ar] = v.y;
            As[slot * 4 + 2][ar] = v.z;
            As[slot * 4 + 3][ar] = v.w;
        }
        // stage W1 tile [k][n]
        #pragma unroll
        for (int i = 0; i < 4; ++i) {
            int col = bcq * 4 + i * 32;
            float4 w = *reinterpret_cast<const float4*>(
                &W1[(size_t)(k0 + bkr) * HIDN + col]);
            int sc = col + ((col >> 5) << 2);
            *reinterpret_cast<float4*>(&Bs[bkr][sc]) = w;
        }
        __syncthreads();
        #pragma unroll
        for (int k = 0; k < 32; ++k) {
            float4 a  = *reinterpret_cast<const float4*>(&As[k][ty * 4]);
            float4 w0 = *reinterpret_cast<const float4*>(&Bs[k][bc]);
            float4 w1 = *reinterpret_cast<const float4*>(&Bs[k][bc + 4]);
            float av[4] = {a.x, a.y, a.z, a.w};
            float bv[8] = {w0.x, w0.y, w0.z, w0.w, w1.x, w1.y, w1.z, w1.w};
            #pragma unroll
            for (int i = 0; i < 4; ++i)
                #pragma unroll
                for (int j = 0; j < 8; ++j)
                    acc[i][j] = fmaf(av[i], bv[j], acc[i][j]);
        }
        __syncthreads();
    }

    // epilogue: bias + exact GELU, store h
    #pragma unroll
    for (int i = 0; i < 4; ++i) {
        int row = m0 + ty * 4 + i;
        #pragma unroll
        for (int j = 0; j < 8; ++j) {
            float y = acc[i][j] + b1[tx * 8 + j];
            acc[i][j] = 0.5f * y * (1.0f + erff(y * 0.70710678118654752f));
        }
        float4 s0 = {acc[i][0], acc[i][1], acc[i][2], acc[i][3]};
        float4 s1 = {acc[i][4], acc[i][5], acc[i][6], acc[i][7]};
        *reinterpret_cast<float4*>(&Hout[(size_t)row * HIDN + tx * 8])     = s0;
        *reinterpret_cast<float4*>(&Hout[(size_t)row * HIDN + tx * 8 + 4]) = s1;
    }
}

// ---------------------------------------------------------------------------
// Kernel B: y2 = h @ W2 + b2; z = pi*tanh(y2); nu = wrap(z - theta); u = K*nu
// Tile: 32 rows (l) x 256 channels; 256 threads; micro 4(l) x 8(hc).
// ---------------------------------------------------------------------------
__global__ __launch_bounds__(256) void k_gemm2_u(
    const float* __restrict__ Hin,    // [16384,128]
    const float* __restrict__ W2,     // [128,256]
    const float* __restrict__ b2,     // [256]
    const float* __restrict__ theta,  // [16384,256]
    const float* __restrict__ logPi,  // [256]
    const float* __restrict__ logR,   // [256]
    float* __restrict__ Ubuf)         // [16384,256]
{
    __shared__ float hs[32][132];     // [l][j]
    __shared__ float ws[32][288];     // [j][hc], +4 pad per 32 cols

    const int tid = threadIdx.x;
    const int m0  = blockIdx.x * 32;

    // stage h tile (all 128 j)
    {
        int r = tid >> 3, q = tid & 7;
        #pragma unroll
        for (int i = 0; i < 4; ++i) {
            int col = q * 4 + i * 32;
            float4 v = *reinterpret_cast<const float4*>(
                &Hin[(size_t)(m0 + r) * HIDN + col]);
            *reinterpret_cast<float4*>(&hs[r][col]) = v;
        }
    }

    const int ly = tid >> 5;   // 0..7  -> rows ly*4..+3
    const int cx = tid & 31;   // 0..31 -> cols cx*8..+7
    const int wc = cx * 8 + ((cx >> 2) << 2);

    float acc[4][8];
    #pragma unroll
    for (int i = 0; i < 4; ++i)
        #pragma unroll
        for (int c = 0; c < 8; ++c) acc[i][c] = 0.0f;

    const int jr = tid >> 3, cq = tid & 7;
    for (int jc = 0; jc < 4; ++jc) {
        __syncthreads();   // hs ready (1st iter) / ws consumed (later iters)
        #pragma unroll
        for (int i = 0; i < 8; ++i) {
            int col = cq * 4 + i * 32;
            float4 v = *reinterpret_cast<const float4*>(
                &W2[(size_t)(jc * 32 + jr) * HNB + col]);
            int sc = col + ((col >> 5) << 2);
            *reinterpret_cast<float4*>(&ws[jr][sc]) = v;
        }
        __syncthreads();
        #pragma unroll
        for (int j4 = 0; j4 < 8; ++j4) {
            float hvf[4][4];
            #pragma unroll
            for (int i = 0; i < 4; ++i) {
                float4 t = *reinterpret_cast<const float4*>(
                    &hs[ly * 4 + i][jc * 32 + j4 * 4]);
                hvf[i][0] = t.x; hvf[i][1] = t.y; hvf[i][2] = t.z; hvf[i][3] = t.w;
            }
            #pragma unroll
            for (int jj = 0; jj < 4; ++jj) {
                float4 w0 = *reinterpret_cast<const float4*>(&ws[j4 * 4 + jj][wc]);
                float4 w1 = *reinterpret_cast<const float4*>(&ws[j4 * 4 + jj][wc + 4]);
                float wv[8] = {w0.x, w0.y, w0.z, w0.w, w1.x, w1.y, w1.z, w1.w};
                #pragma unroll
                for (int i = 0; i < 4; ++i)
                    #pragma unroll
                    for (int c = 0; c < 8; ++c)
                        acc[i][c] = fmaf(hvf[i][jj], wv[c], acc[i][c]);
            }
        }
    }

    // per-thread channel constants
    float Kv[8], b2v[8];
    {
        float4 lp0 = *reinterpret_cast<const float4*>(&logPi[cx * 8]);
        float4 lp1 = *reinterpret_cast<const float4*>(&logPi[cx * 8 + 4]);
        float4 lr0 = *reinterpret_cast<const float4*>(&logR[cx * 8]);
        float4 lr1 = *reinterpret_cast<const float4*>(&logR[cx * 8 + 4]);
        float4 bb0 = *reinterpret_cast<const float4*>(&b2[cx * 8]);
        float4 bb1 = *reinterpret_cast<const float4*>(&b2[cx * 8 + 4]);
        float lpv[8] = {lp0.x, lp0.y, lp0.z, lp0.w, lp1.x, lp1.y, lp1.z, lp1.w};
        float lrv[8] = {lr0.x, lr0.y, lr0.z, lr0.w, lr1.x, lr1.y, lr1.z, lr1.w};
        float bbv[8] = {bb0.x, bb0.y, bb0.z, bb0.w, bb1.x, bb1.y, bb1.z, bb1.w};
        #pragma unroll
        for (int c = 0; c < 8; ++c) {
            float Pi = expf(lpv[c]);
            float R  = expf(lrv[c]);
            Kv[c]  = Pi / fmaxf(Pi + R, 1e-8f);
            b2v[c] = bbv[c];
        }
    }

    #pragma unroll
    for (int i = 0; i < 4; ++i) {
        int m = m0 + ly * 4 + i;
        float4 t0 = *reinterpret_cast<const float4*>(&theta[(size_t)m * HNB + cx * 8]);
        float4 t1 = *reinterpret_cast<const float4*>(&theta[(size_t)m * HNB + cx * 8 + 4]);
        float thv[8] = {t0.x, t0.y, t0.z, t0.w, t1.x, t1.y, t1.z, t1.w};
        float uv[8];
        #pragma unroll
        for (int c = 0; c < 8; ++c) {
            float y    = acc[i][c] + b2v[c];
            float z    = 3.14159265358979323846f * tanhf(y);
            float diff = z - thv[c];
            float kq   = rintf(diff * 0.15915494309189533577f);
            // wrapped residual; do the 2*pi*k subtraction in double to keep
            // the wrap decision aligned with the fp64 numpy reference
            float nu = (float)((double)diff - (double)kq * 6.283185307179586476925286766559);
            uv[c] = Kv[c] * nu;
        }
        float4 s0 = {uv[0], uv[1], uv[2], uv[3]};
        float4 s1 = {uv[4], uv[5], uv[6], uv[7]};
        *reinterpret_cast<float4*>(&Ubuf[(size_t)m * HNB + cx * 8])     = s0;
        *reinterpret_cast<float4*>(&Ubuf[(size_t)m * HNB + cx * 8 + 4]) = s1;
    }
}

// ---------------------------------------------------------------------------
// Chunked affine scan (constant alpha per channel).
// d_t = alpha*d_{t-1} + u_t decomposed into 64-step chunks:
//   K1: per-chunk local terminal value (carry candidate)
//   K2: exclusive scan of carries across chunks: D_s = alpha^64*D_{s-1}+c_{s-1}
//   K3: re-walk chunk from incoming carry, out0 = theta + d
// One thread per channel -> fully coalesced 1KB/row accesses.
// ---------------------------------------------------------------------------
__global__ __launch_bounds__(256) void k_scan_carry(
    const float* __restrict__ Ubuf,
    const float* __restrict__ logPi,
    const float* __restrict__ logR,
    float* __restrict__ carry)      // [NBAT*NCH][256]
{
    const int c  = threadIdx.x;
    const int ch = blockIdx.x & (NCH - 1);
    const int b  = blockIdx.x >> 6;           // NCH == 64
    float Pi = expf(logPi[c]);
    float R  = expf(logR[c]);
    float alpha = 1.0f - Pi / fmaxf(Pi + R, 1e-8f);
    size_t base = ((size_t)b * LLEN + (size_t)ch * CL) * HNB + c;
    float uv[CL];
    #pragma unroll
    for (int i = 0; i < CL; ++i)
        uv[i] = Ubuf[base + (size_t)i * HNB];
    float d = 0.0f;
    #pragma unroll
    for (int i = 0; i < CL; ++i)
        d = fmaf(alpha, d, uv[i]);
    carry[(size_t)blockIdx.x * HNB + c] = d;
}

__global__ __launch_bounds__(256) void k_scan_carry_scan(
    const float* __restrict__ logPi,
    const float* __restrict__ logR,
    float* __restrict__ carry)      // in-place -> incoming carry per chunk
{
    const int c = threadIdx.x;
    const int b = blockIdx.x;
    float Pi = expf(logPi[c]);
    float R  = expf(logR[c]);
    float alpha = 1.0f - Pi / fmaxf(Pi + R, 1e-8f);
    float A = alpha;                 // alpha^64 via 6 squarings
    #pragma unroll
    for (int i = 0; i < 6; ++i) A = A * A;
    size_t base = (size_t)b * NCH * HNB + c;
    float cv[NCH];
    #pragma unroll
    for (int s = 0; s < NCH; ++s)
        cv[s] = carry[base + (size_t)s * HNB];
    float D = 0.0f;
    #pragma unroll
    for (int s = 0; s < NCH; ++s) {
        float t = cv[s];
        carry[base + (size_t)s * HNB] = D;   // exclusive: incoming for chunk s
        D = fmaf(A, D, t);
    }
}

__global__ __launch_bounds__(256) void k_scan_apply(
    const float* __restrict__ Ubuf,
    const float* __restrict__ theta,
    const float* __restrict__ carry,
    const float* __restrict__ logPi,
    const float* __restrict__ logR,
    float* __restrict__ out0)
{
    const int c  = threadIdx.x;
    const int ch = blockIdx.x & (NCH - 1);
    const int b  = blockIdx.x >> 6;
    float Pi = expf(logPi[c]);
    float R  = expf(logR[c]);
    float alpha = 1.0f - Pi / fmaxf(Pi + R, 1e-8f);
    float d = carry[(size_t)blockIdx.x * HNB + c];
    size_t base = ((size_t)b * LLEN + (size_t)ch * CL) * HNB + c;
    float uv[CL];
    #pragma unroll
    for (int i = 0; i < CL; ++i)
        uv[i] = Ubuf[base + (size_t)i * HNB];
    #pragma unroll
    for (int i = 0; i < CL; ++i) {
        d = fmaf(alpha, d, uv[i]);
        out0[base + (size_t)i * HNB] = theta[base + (size_t)i * HNB] + d;
    }
}

// ---------------------------------------------------------------------------
// Kernel D: broadcast-constant outputs 1..3 (Pi, K, R)
// ---------------------------------------------------------------------------
__global__ __launch_bounds__(256) void k_fill(
    const float* __restrict__ logPi,
    const float* __restrict__ logR,
    float* __restrict__ out1,
    float* __restrict__ out2,
    float* __restrict__ out3)
{
    size_t s = (size_t)blockIdx.x * 256 + threadIdx.x;  // float4 slot
    int c0 = (int)((s & 63) << 2);                       // channel of elem 0
    float4 lp = *reinterpret_cast<const float4*>(&logPi[c0]);
    float4 lr = *reinterpret_cast<const float4*>(&logR[c0]);
    float4 Pi = {expf(lp.x), expf(lp.y), expf(lp.z), expf(lp.w)};
    float4 Rr = {expf(lr.x), expf(lr.y), expf(lr.z), expf(lr.w)};
    float4 Kk = {Pi.x / fmaxf(Pi.x + Rr.x, 1e-8f),
                 Pi.y / fmaxf(Pi.y + Rr.y, 1e-8f),
                 Pi.z / fmaxf(Pi.z + Rr.z, 1e-8f),
                 Pi.w / fmaxf(Pi.w + Rr.w, 1e-8f)};
    *reinterpret_cast<float4*>(&out1[s * 4]) = Pi;
    *reinterpret_cast<float4*>(&out2[s * 4]) = Kk;
    *reinterpret_cast<float4*>(&out3[s * 4]) = Rr;
}

extern "C" void kernel_launch(void* const* d_in, const int* in_sizes, int n_in,
                              void* d_out, int out_size, void* d_ws, size_t ws_size,
                              hipStream_t stream) {
    const float* theta   = (const float*)d_in[0];
    const float* content = (const float*)d_in[1];
    const float* W1      = (const float*)d_in[2];
    const float* b1      = (const float*)d_in[3];
    const float* W2      = (const float*)d_in[4];
    const float* b2      = (const float*)d_in[5];
    const float* logPi   = (const float*)d_in[6];
    const float* logR    = (const float*)d_in[7];

    float* out  = (float*)d_out;
    float* out0 = out;
    float* out1 = out + (size_t)MTOT * HNB;
    float* out2 = out + (size_t)2 * MTOT * HNB;
    float* out3 = out + (size_t)3 * MTOT * HNB;

    float* Hbuf  = out1;  // scratch until k_fill overwrites (2.1M floats)
    float* Ubuf  = out2;  // scratch until k_fill overwrites (4.19M floats)
    float* Cbuf  = out3;  // carry scratch (64K floats) until k_fill overwrites

    hipLaunchKernelGGL(k_gemm1_gelu, dim3(MTOT / 64), dim3(256), 0, stream,
                       content, W1, b1, Hbuf);
    hipLaunchKernelGGL(k_gemm2_u, dim3(MTOT / 32), dim3(256), 0, stream,
                       Hbuf, W2, b2, theta, logPi, logR, Ubuf);
    hipLaunchKernelGGL(k_scan_carry, dim3(NBAT * NCH), dim3(256), 0, stream,
                       Ubuf, logPi, logR, Cbuf);
    hipLaunchKernelGGL(k_scan_carry_scan, dim3(NBAT), dim3(256), 0, stream,
                       logPi, logR, Cbuf);
    hipLaunchKernelGGL(k_scan_apply, dim3(NBAT * NCH), dim3(256), 0, stream,
                       Ubuf, theta, Cbuf, logPi, logR, out0);
    hipLaunchKernelGGL(k_fill, dim3((MTOT * HNB / 4) / 256), dim3(256), 0, stream,
                       logPi, logR, out1, out2, out3);
}

// Round 3
// 119.411 us; speedup vs baseline: 3.3489x; 1.1365x over previous
//
#include <hip/hip_runtime.h>
#include <hip/hip_bf16.h>
#include <math.h>

// Problem geometry
#define MTOT  16384      // B*L = 4*4096
#define DM    1024
#define HIDN  128
#define HNB   256        // H*NB
#define LLEN  4096
#define NBAT  4
#define CL    64         // scan chunk length
#define NCH   (LLEN/CL)  // 64 chunks per sequence
#define KSPL  4          // GEMM1 K-split factor
#define KRNG  (DM/KSPL)  // 256 K per split
#define HSZ   ((size_t)MTOT * HIDN)   // 2,097,152 floats per partial

// ---------------------------------------------------------------------------
// Kernel A: partial GEMM  P[split] = content[:, kr] @ W1[kr, :]
// BM=64, BN=128, BK=32; 256 threads; micro-tile 4(M)x8(N) per thread.
// Grid (256 m-tiles, 4 k-splits) = 1024 blocks -> 4 blocks/CU.
// ---------------------------------------------------------------------------
__global__ __launch_bounds__(256) void k_gemm1_part(
    const float* __restrict__ A,    // content [16384,1024]
    const float* __restrict__ W1,   // [1024,128]
    float* __restrict__ Pa,         // splits 0,1 (out2 region)
    float* __restrict__ Pb)         // splits 2,3 (out3 region)
{
    __shared__ float As[32][68];    // [k][m], padded
    __shared__ float Bs[32][140];   // [k][n], +4 pad per 32 cols (bank swizzle)

    const int tid   = threadIdx.x;
    const int m0    = blockIdx.x * 64;
    const int split = blockIdx.y;
    const int ty  = tid >> 4;       // 0..15 -> rows ty*4..+3
    const int tx  = tid & 15;       // 0..15 -> cols tx*8..+7
    const int bc  = tx * 8 + ((tx >> 2) << 2);  // swizzled col base

    const int ar  = tid >> 2;       // 0..63  (A stage row)
    const int as  = tid & 3;        // A stage slot
    const int bkr = tid >> 3;       // 0..31  (B stage k-row)
    const int bcq = tid & 7;

    float acc[4][8];
    #pragma unroll
    for (int i = 0; i < 4; ++i)
        #pragma unroll
        for (int j = 0; j < 8; ++j) acc[i][j] = 0.0f;

    for (int kt = 0; kt < KRNG / 32; ++kt) {
        const int k0 = split * KRNG + kt * 32;
        // stage A tile, transposed into [k][m]
        #pragma unroll
        for (int i = 0; i < 2; ++i) {
            int slot = as + i * 4;  // 0..7 (float4 slot within 32 k's)
            float4 v = *reinterpret_cast<const float4*>(
                &A[(size_t)(m0 + ar) * DM + k0 + slot * 4]);
            As[slot * 4 + 0][ar] = v.x;
            As[slot * 4 + 1][ar] = v.y;
            As[slot * 4 + 2][ar] = v.z;
            As[slot * 4 + 3][ar] = v.w;
        }
        // stage W1 tile [k][n]
        #pragma unroll
        for (int i = 0; i < 4; ++i) {
            int col = bcq * 4 + i * 32;
            float4 w = *reinterpret_cast<const float4*>(
                &W1[(size_t)(k0 + bkr) * HIDN + col]);
            int sc = col + ((col >> 5) << 2);
            *reinterpret_cast<float4*>(&Bs[bkr][sc]) = w;
        }
        __syncthreads();
        #pragma unroll
        for (int k = 0; k < 32; ++k) {
            float4 a  = *reinterpret_cast<const float4*>(&As[k][ty * 4]);
            float4 w0 = *reinterpret_cast<const float4*>(&Bs[k][bc]);
            float4 w1 = *reinterpret_cast<const float4*>(&Bs[k][bc + 4]);
            float av[4] = {a.x, a.y, a.z, a.w};
            float bv[8] = {w0.x, w0.y, w0.z, w0.w, w1.x, w1.y, w1.z, w1.w};
            #pragma unroll
            for (int i = 0; i < 4; ++i)
                #pragma unroll
                for (int j = 0; j < 8; ++j)
                    acc[i][j] = fmaf(av[i], bv[j], acc[i][j]);
        }
        __syncthreads();
    }

    float* P = (split < 2) ? (Pa + (size_t)split * HSZ)
                           : (Pb + (size_t)(split - 2) * HSZ);
    #pragma unroll
    for (int i = 0; i < 4; ++i) {
        int row = m0 + ty * 4 + i;
        float4 s0 = {acc[i][0], acc[i][1], acc[i][2], acc[i][3]};
        float4 s1 = {acc[i][4], acc[i][5], acc[i][6], acc[i][7]};
        *reinterpret_cast<float4*>(&P[(size_t)row * HIDN + tx * 8])     = s0;
        *reinterpret_cast<float4*>(&P[(size_t)row * HIDN + tx * 8 + 4]) = s1;
    }
}

// ---------------------------------------------------------------------------
// Kernel A2: H = gelu(P0+P1+P2+P3 + b1)
// ---------------------------------------------------------------------------
__global__ __launch_bounds__(256) void k_h_gelu(
    const float* __restrict__ Pa,
    const float* __restrict__ Pb,
    const float* __restrict__ b1,
    float* __restrict__ Hout)
{
    size_t s = (size_t)blockIdx.x * 256 + threadIdx.x;   // float4 slot
    size_t off = s * 4;
    int col = (int)(off & (HIDN - 1));
    float4 p0 = *reinterpret_cast<const float4*>(&Pa[off]);
    float4 p1 = *reinterpret_cast<const float4*>(&Pa[HSZ + off]);
    float4 p2 = *reinterpret_cast<const float4*>(&Pb[off]);
    float4 p3 = *reinterpret_cast<const float4*>(&Pb[HSZ + off]);
    float4 bb = *reinterpret_cast<const float4*>(&b1[col]);
    float y[4] = {(p0.x + p1.x) + (p2.x + p3.x) + bb.x,
                  (p0.y + p1.y) + (p2.y + p3.y) + bb.y,
                  (p0.z + p1.z) + (p2.z + p3.z) + bb.z,
                  (p0.w + p1.w) + (p2.w + p3.w) + bb.w};
    float4 h;
    h.x = 0.5f * y[0] * (1.0f + erff(y[0] * 0.70710678118654752f));
    h.y = 0.5f * y[1] * (1.0f + erff(y[1] * 0.70710678118654752f));
    h.z = 0.5f * y[2] * (1.0f + erff(y[2] * 0.70710678118654752f));
    h.w = 0.5f * y[3] * (1.0f + erff(y[3] * 0.70710678118654752f));
    *reinterpret_cast<float4*>(&Hout[off]) = h;
}

// ---------------------------------------------------------------------------
// Kernel B: y2 = h @ W2 + b2; z = pi*tanh(y2); nu = wrap(z - theta); u = K*nu
// Tile: 32 rows (l) x 256 channels; 256 threads; micro 4(l) x 8(hc).
// ---------------------------------------------------------------------------
__global__ __launch_bounds__(256) void k_gemm2_u(
    const float* __restrict__ Hin,    // [16384,128]
    const float* __restrict__ W2,     // [128,256]
    const float* __restrict__ b2,     // [256]
    const float* __restrict__ theta,  // [16384,256]
    const float* __restrict__ logPi,  // [256]
    const float* __restrict__ logR,   // [256]
    float* __restrict__ Ubuf)         // [16384,256]
{
    __shared__ float hs[32][132];     // [l][j]
    __shared__ float ws[32][288];     // [j][hc], +4 pad per 32 cols

    const int tid = threadIdx.x;
    const int m0  = blockIdx.x * 32;

    // stage h tile (all 128 j)
    {
        int r = tid >> 3, q = tid & 7;
        #pragma unroll
        for (int i = 0; i < 4; ++i) {
            int col = q * 4 + i * 32;
            float4 v = *reinterpret_cast<const float4*>(
                &Hin[(size_t)(m0 + r) * HIDN + col]);
            *reinterpret_cast<float4*>(&hs[r][col]) = v;
        }
    }

    const int ly = tid >> 5;   // 0..7  -> rows ly*4..+3
    const int cx = tid & 31;   // 0..31 -> cols cx*8..+7
    const int wc = cx * 8 + ((cx >> 2) << 2);

    float acc[4][8];
    #pragma unroll
    for (int i = 0; i < 4; ++i)
        #pragma unroll
        for (int c = 0; c < 8; ++c) acc[i][c] = 0.0f;

    const int jr = tid >> 3, cq = tid & 7;
    for (int jc = 0; jc < 4; ++jc) {
        __syncthreads();   // hs ready (1st iter) / ws consumed (later iters)
        #pragma unroll
        for (int i = 0; i < 8; ++i) {
            int col = cq * 4 + i * 32;
            float4 v = *reinterpret_cast<const float4*>(
                &W2[(size_t)(jc * 32 + jr) * HNB + col]);
            int sc = col + ((col >> 5) << 2);
            *reinterpret_cast<float4*>(&ws[jr][sc]) = v;
        }
        __syncthreads();
        #pragma unroll
        for (int j4 = 0; j4 < 8; ++j4) {
            float hvf[4][4];
            #pragma unroll
            for (int i = 0; i < 4; ++i) {
                float4 t = *reinterpret_cast<const float4*>(
                    &hs[ly * 4 + i][jc * 32 + j4 * 4]);
                hvf[i][0] = t.x; hvf[i][1] = t.y; hvf[i][2] = t.z; hvf[i][3] = t.w;
            }
            #pragma unroll
            for (int jj = 0; jj < 4; ++jj) {
                float4 w0 = *reinterpret_cast<const float4*>(&ws[j4 * 4 + jj][wc]);
                float4 w1 = *reinterpret_cast<const float4*>(&ws[j4 * 4 + jj][wc + 4]);
                float wv[8] = {w0.x, w0.y, w0.z, w0.w, w1.x, w1.y, w1.z, w1.w};
                #pragma unroll
                for (int i = 0; i < 4; ++i)
                    #pragma unroll
                    for (int c = 0; c < 8; ++c)
                        acc[i][c] = fmaf(hvf[i][jj], wv[c], acc[i][c]);
            }
        }
    }

    // per-thread channel constants
    float Kv[8], b2v[8];
    {
        float4 lp0 = *reinterpret_cast<const float4*>(&logPi[cx * 8]);
        float4 lp1 = *reinterpret_cast<const float4*>(&logPi[cx * 8 + 4]);
        float4 lr0 = *reinterpret_cast<const float4*>(&logR[cx * 8]);
        float4 lr1 = *reinterpret_cast<const float4*>(&logR[cx * 8 + 4]);
        float4 bb0 = *reinterpret_cast<const float4*>(&b2[cx * 8]);
        float4 bb1 = *reinterpret_cast<const float4*>(&b2[cx * 8 + 4]);
        float lpv[8] = {lp0.x, lp0.y, lp0.z, lp0.w, lp1.x, lp1.y, lp1.z, lp1.w};
        float lrv[8] = {lr0.x, lr0.y, lr0.z, lr0.w, lr1.x, lr1.y, lr1.z, lr1.w};
        float bbv[8] = {bb0.x, bb0.y, bb0.z, bb0.w, bb1.x, bb1.y, bb1.z, bb1.w};
        #pragma unroll
        for (int c = 0; c < 8; ++c) {
            float Pi = expf(lpv[c]);
            float R  = expf(lrv[c]);
            Kv[c]  = Pi / fmaxf(Pi + R, 1e-8f);
            b2v[c] = bbv[c];
        }
    }

    #pragma unroll
    for (int i = 0; i < 4; ++i) {
        int m = m0 + ly * 4 + i;
        float4 t0 = *reinterpret_cast<const float4*>(&theta[(size_t)m * HNB + cx * 8]);
        float4 t1 = *reinterpret_cast<const float4*>(&theta[(size_t)m * HNB + cx * 8 + 4]);
        float thv[8] = {t0.x, t0.y, t0.z, t0.w, t1.x, t1.y, t1.z, t1.w};
        float uv[8];
        #pragma unroll
        for (int c = 0; c < 8; ++c) {
            float y    = acc[i][c] + b2v[c];
            float z    = 3.14159265358979323846f * tanhf(y);
            float diff = z - thv[c];
            float kq   = rintf(diff * 0.15915494309189533577f);
            // wrapped residual; 2*pi*k subtraction in double to keep the wrap
            // decision aligned with the fp64 numpy reference
            float nu = (float)((double)diff - (double)kq * 6.283185307179586476925286766559);
            uv[c] = Kv[c] * nu;
        }
        float4 s0 = {uv[0], uv[1], uv[2], uv[3]};
        float4 s1 = {uv[4], uv[5], uv[6], uv[7]};
        *reinterpret_cast<float4*>(&Ubuf[(size_t)m * HNB + cx * 8])     = s0;
        *reinterpret_cast<float4*>(&Ubuf[(size_t)m * HNB + cx * 8 + 4]) = s1;
    }
}

// ---------------------------------------------------------------------------
// Chunked affine scan (constant alpha per channel).
// ---------------------------------------------------------------------------
__global__ __launch_bounds__(256) void k_scan_carry(
    const float* __restrict__ Ubuf,
    const float* __restrict__ logPi,
    const float* __restrict__ logR,
    float* __restrict__ carry)      // [NBAT*NCH][256]
{
    const int c  = threadIdx.x;
    const int ch = blockIdx.x & (NCH - 1);
    const int b  = blockIdx.x >> 6;           // NCH == 64
    float Pi = expf(logPi[c]);
    float R  = expf(logR[c]);
    float alpha = 1.0f - Pi / fmaxf(Pi + R, 1e-8f);
    size_t base = ((size_t)b * LLEN + (size_t)ch * CL) * HNB + c;
    float uv[CL];
    #pragma unroll
    for (int i = 0; i < CL; ++i)
        uv[i] = Ubuf[base + (size_t)i * HNB];
    float d = 0.0f;
    #pragma unroll
    for (int i = 0; i < CL; ++i)
        d = fmaf(alpha, d, uv[i]);
    carry[(size_t)blockIdx.x * HNB + c] = d;
}

__global__ __launch_bounds__(256) void k_scan_carry_scan(
    const float* __restrict__ logPi,
    const float* __restrict__ logR,
    float* __restrict__ carry)      // in-place -> incoming carry per chunk
{
    const int c = threadIdx.x;
    const int b = blockIdx.x;
    float Pi = expf(logPi[c]);
    float R  = expf(logR[c]);
    float alpha = 1.0f - Pi / fmaxf(Pi + R, 1e-8f);
    float A = alpha;                 // alpha^64 via 6 squarings
    #pragma unroll
    for (int i = 0; i < 6; ++i) A = A * A;
    size_t base = (size_t)b * NCH * HNB + c;
    float cv[NCH];
    #pragma unroll
    for (int s = 0; s < NCH; ++s)
        cv[s] = carry[base + (size_t)s * HNB];
    float D = 0.0f;
    #pragma unroll
    for (int s = 0; s < NCH; ++s) {
        float t = cv[s];
        carry[base + (size_t)s * HNB] = D;   // exclusive: incoming for chunk s
        D = fmaf(A, D, t);
    }
}

__global__ __launch_bounds__(256) void k_scan_apply(
    const float* __restrict__ Ubuf,
    const float* __restrict__ theta,
    const float* __restrict__ carry,
    const float* __restrict__ logPi,
    const float* __restrict__ logR,
    float* __restrict__ out0)
{
    const int c  = threadIdx.x;
    const int ch = blockIdx.x & (NCH - 1);
    const int b  = blockIdx.x >> 6;
    float Pi = expf(logPi[c]);
    float R  = expf(logR[c]);
    float alpha = 1.0f - Pi / fmaxf(Pi + R, 1e-8f);
    float d = carry[(size_t)blockIdx.x * HNB + c];
    size_t base = ((size_t)b * LLEN + (size_t)ch * CL) * HNB + c;
    float uv[CL];
    #pragma unroll
    for (int i = 0; i < CL; ++i)
        uv[i] = Ubuf[base + (size_t)i * HNB];
    #pragma unroll
    for (int i = 0; i < CL; ++i) {
        d = fmaf(alpha, d, uv[i]);
        out0[base + (size_t)i * HNB] = theta[base + (size_t)i * HNB] + d;
    }
}

// ---------------------------------------------------------------------------
// Kernel D: broadcast-constant outputs 1..3 (Pi, K, R)
// ---------------------------------------------------------------------------
__global__ __launch_bounds__(256) void k_fill(
    const float* __restrict__ logPi,
    const float* __restrict__ logR,
    float* __restrict__ out1,
    float* __restrict__ out2,
    float* __restrict__ out3)
{
    size_t s = (size_t)blockIdx.x * 256 + threadIdx.x;  // float4 slot
    int c0 = (int)((s & 63) << 2);                       // channel of elem 0
    float4 lp = *reinterpret_cast<const float4*>(&logPi[c0]);
    float4 lr = *reinterpret_cast<const float4*>(&logR[c0]);
    float4 Pi = {expf(lp.x), expf(lp.y), expf(lp.z), expf(lp.w)};
    float4 Rr = {expf(lr.x), expf(lr.y), expf(lr.z), expf(lr.w)};
    float4 Kk = {Pi.x / fmaxf(Pi.x + Rr.x, 1e-8f),
                 Pi.y / fmaxf(Pi.y + Rr.y, 1e-8f),
                 Pi.z / fmaxf(Pi.z + Rr.z, 1e-8f),
                 Pi.w / fmaxf(Pi.w + Rr.w, 1e-8f)};
    *reinterpret_cast<float4*>(&out1[s * 4]) = Pi;
    *reinterpret_cast<float4*>(&out2[s * 4]) = Kk;
    *reinterpret_cast<float4*>(&out3[s * 4]) = Rr;
}

extern "C" void kernel_launch(void* const* d_in, const int* in_sizes, int n_in,
                              void* d_out, int out_size, void* d_ws, size_t ws_size,
                              hipStream_t stream) {
    const float* theta   = (const float*)d_in[0];
    const float* content = (const float*)d_in[1];
    const float* W1      = (const float*)d_in[2];
    const float* b1      = (const float*)d_in[3];
    const float* W2      = (const float*)d_in[4];
    const float* b2      = (const float*)d_in[5];
    const float* logPi   = (const float*)d_in[6];
    const float* logR    = (const float*)d_in[7];

    float* out  = (float*)d_out;
    float* out0 = out;
    float* out1 = out + (size_t)MTOT * HNB;
    float* out2 = out + (size_t)2 * MTOT * HNB;
    float* out3 = out + (size_t)3 * MTOT * HNB;

    // Scratch staging inside output regions (all overwritten by k_fill last):
    //   out2: partials P0,P1 -> later Ubuf
    //   out3: partials P2,P3 -> later carry
    //   out1: H              -> later filled
    float* Pa   = out2;
    float* Pb   = out3;
    float* Hbuf = out1;
    float* Ubuf = out2;
    float* Cbuf = out3;

    hipLaunchKernelGGL(k_gemm1_part, dim3(MTOT / 64, KSPL), dim3(256), 0, stream,
                       content, W1, Pa, Pb);
    hipLaunchKernelGGL(k_h_gelu, dim3((int)(HSZ / 4 / 256)), dim3(256), 0, stream,
                       Pa, Pb, b1, Hbuf);
    hipLaunchKernelGGL(k_gemm2_u, dim3(MTOT / 32), dim3(256), 0, stream,
                       Hbuf, W2, b2, theta, logPi, logR, Ubuf);
    hipLaunchKernelGGL(k_scan_carry, dim3(NBAT * NCH), dim3(256), 0, stream,
                       Ubuf, logPi, logR, Cbuf);
    hipLaunchKernelGGL(k_scan_carry_scan, dim3(NBAT), dim3(256), 0, stream,
                       logPi, logR, Cbuf);
    hipLaunchKernelGGL(k_scan_apply, dim3(NBAT * NCH), dim3(256), 0, stream,
                       Ubuf, theta, Cbuf, logPi, logR, out0);
    hipLaunchKernelGGL(k_fill, dim3((MTOT * HNB / 4) / 256), dim3(256), 0, stream,
                       logPi, logR, out1, out2, out3);
}

// Round 4
// 74.216 us; speedup vs baseline: 5.3883x; 1.6090x over previous
//
#include <hip/hip_runtime.h>
#include <math.h>

// Problem geometry
#define MTOT  16384      // B*L
#define DM    1024
#define HIDN  128
#define HNB   256
#define LLEN  4096
#define NBAT  4
#define CL    64         // chunk length == rows per k_mega block
#define NCH   64         // chunks per sequence

typedef _Float16 v8h __attribute__((ext_vector_type(8)));
typedef float    v4f __attribute__((ext_vector_type(4)));
#define MFMA16(a,b,c) __builtin_amdgcn_mfma_f32_16x16x32_f16((a),(b),(c),0,0,0)

// Weight blob layout (in out1 region, overwritten by fills in K3):
//  [0,655360):        W1 k-tiles kt=0..31, 20480 B each: {W1h[n=128][40] fp16 | W1l[128][40]}
//  [655360,819200):   W2 k-tiles ks=0..3, 40960 B each: {W2h[n=256][40] | W2l[256][40]}
// rows are 80 B (32 k + 8 pad fp16) -> 16B-aligned b128 frag reads, ~2-way banks.
#define W1BLOB_TILE 20480
#define W2BLOB_BASE 655360
#define W2BLOB_TILE 40960

// k_mega LDS map (dynamic, 133120 B):
//  P1 GEMM1 dbuf: buf b @ b*30720: Ah[64][40]@0 (5120), Al@5120, Wh[128][40]@10240, Wl@20480
//  P3 H:          Hh[64][136]@61440 (17408), Hl@78848  (alive through GEMM2)
//  P4 W2 stage:   @0..40960 (A/W dead)
//  P5 u buf:      @0..66560 [64][260] f32 (W2 dead);  theta/S buf: @66560..133120 (H dead)
#define AW_BUF   30720
#define HH_OFF   61440
#define HL_OFF   78848
#define U_OFF    0
#define TH_OFF   66560
#define SMEM_SZ  133120

// ---------------------------------------------------------------------------
// K0: convert+transpose+pad weights into fp16 split blobs.
//     Xh = fp16(x); Xl = fp16((x - Xh) * 4096)   (scaled low part)
// ---------------------------------------------------------------------------
__global__ __launch_bounds__(256) void k_prep(
    const float* __restrict__ W1,   // [1024][128]
    const float* __restrict__ W2,   // [128][256]
    char* __restrict__ blobs)
{
    __shared__ float lds[32][260];
    const int t = threadIdx.x, blk = blockIdx.x;
    if (blk < 32) {
        const int k0 = blk * 32;
        #pragma unroll
        for (int i = 0; i < 4; ++i) {
            int j = t + i * 256;                 // 1024 float4 jobs
            int k = j >> 5, n4 = (j & 31) << 2;
            *(float4*)&lds[k][n4] = *(const float4*)&W1[(size_t)(k0 + k) * HIDN + n4];
        }
        __syncthreads();
        const int n = t >> 1, kh = t & 1;
        union { _Float16 h[16]; int2 v[4]; } uh, ul;
        #pragma unroll
        for (int kk = 0; kk < 16; ++kk) {
            float v = lds[kh * 16 + kk][n];
            _Float16 hh = (_Float16)v;
            uh.h[kk] = hh;
            ul.h[kk] = (_Float16)((v - (float)hh) * 4096.f);
        }
        char* bh = blobs + blk * W1BLOB_TILE + n * 80 + kh * 32;
        #pragma unroll
        for (int i = 0; i < 4; ++i) {
            *(int2*)(bh + i * 8)         = uh.v[i];
            *(int2*)(bh + 10240 + i * 8) = ul.v[i];
        }
        if (kh == 1) {               // zero the 8-fp16 pad tail of each row
            int2 z; z.x = 0; z.y = 0;
            char* ph = blobs + blk * W1BLOB_TILE + n * 80 + 64;
            *(int2*)(ph) = z; *(int2*)(ph + 8) = z;
            *(int2*)(ph + 10240) = z; *(int2*)(ph + 10240 + 8) = z;
        }
    } else {
        const int ks = blk - 32, k0 = ks * 32;
        #pragma unroll
        for (int i = 0; i < 8; ++i) {
            int j = t + i * 256;                 // 2048 float4 jobs
            int k = j >> 6, n4 = (j & 63) << 2;
            *(float4*)&lds[k][n4] = *(const float4*)&W2[(size_t)(k0 + k) * HNB + n4];
        }
        __syncthreads();
        const int n = t;
        union { _Float16 h[40]; int2 v[10]; } uh, ul;
        #pragma unroll
        for (int kk = 0; kk < 32; ++kk) {
            float v = lds[kk][n];
            _Float16 hh = (_Float16)v;
            uh.h[kk] = hh;
            ul.h[kk] = (_Float16)((v - (float)hh) * 4096.f);
        }
        #pragma unroll
        for (int kk = 32; kk < 40; ++kk) { uh.h[kk] = (_Float16)0.f; ul.h[kk] = (_Float16)0.f; }
        char* bh = blobs + W2BLOB_BASE + ks * W2BLOB_TILE + n * 80;
        #pragma unroll
        for (int i = 0; i < 10; ++i) {
            *(int2*)(bh + i * 8)         = uh.v[i];
            *(int2*)(bh + 20480 + i * 8) = ul.v[i];
        }
    }
}

// ---------------------------------------------------------------------------
// K1: mega kernel. One block = 64 rows = one scan chunk. 512 threads, 8 waves.
//   GEMM1 (fp16-split MFMA, dbuf LDS) -> GELU -> GEMM2 -> z/wrap/u ->
//   in-block local scan -> S = theta + d_loc -> out0; terminal d -> carry slot.
// ---------------------------------------------------------------------------
__global__ __launch_bounds__(512) void k_mega(
    const float* __restrict__ A,      // content [16384][1024]
    const float* __restrict__ theta,  // [16384][256]
    const float* __restrict__ b1, const float* __restrict__ b2,
    const float* __restrict__ logPi, const float* __restrict__ logR,
    const char* __restrict__ blobs,
    float* __restrict__ out0,         // S output
    float* __restrict__ carry)        // out3 region; slot blk*16384+c
{
    extern __shared__ char smem[];
    const int tid  = threadIdx.x;
    const int blk  = blockIdx.x;
    const int m0   = blk * 64;
    const int lane = tid & 63;
    const int wid  = tid >> 6;
    const int ln15 = lane & 15;
    const int q    = lane >> 4;
    const int mp   = wid & 1;     // M half (rows 32*mp..+31)
    const int np   = wid >> 1;    // 0..3: GEMM1 N-pair / GEMM2 N-quad

    // staging indices
    const int arow = tid >> 3, aseg = tid & 7;
    const size_t a_gbase = (size_t)(m0 + arow) * DM + (size_t)aseg * 4;
    const int4* w1blob = (const int4*)blobs;

    // frag LDS byte offsets (within buf base)
    const int aoff0 = (32 * mp + ln15) * 80 + q * 16;
    const int aoff1 = aoff0 + 16 * 80;
    const int woff0 = 10240 + (32 * np + ln15) * 80 + q * 16;
    const int woff1 = woff0 + 16 * 80;

    v4f acc1[2][2], acc2[2][2];
    #pragma unroll
    for (int i = 0; i < 2; ++i)
        #pragma unroll
        for (int j = 0; j < 2; ++j) {
            acc1[i][j] = (v4f){0.f, 0.f, 0.f, 0.f};
            acc2[i][j] = (v4f){0.f, 0.f, 0.f, 0.f};
        }

    union AU { _Float16 h[4]; int2 v; };

    // ---- prologue: stage kt=0 into buf0
    {
        float4 av = *(const float4*)&A[a_gbase];
        int4 w0 = w1blob[tid], w1v = w1blob[tid + 512];
        int4 w2v; if (tid < 256) w2v = w1blob[tid + 1024];
        char* nb = smem;
        AU uh, ul;
        float a4[4] = {av.x, av.y, av.z, av.w};
        #pragma unroll
        for (int e = 0; e < 4; ++e) {
            _Float16 hh = (_Float16)a4[e];
            uh.h[e] = hh; ul.h[e] = (_Float16)((a4[e] - (float)hh) * 4096.f);
        }
        *(int2*)(nb + arow * 80 + aseg * 8)        = uh.v;
        *(int2*)(nb + 5120 + arow * 80 + aseg * 8) = ul.v;
        *(int4*)(nb + 10240 + tid * 16)            = w0;
        *(int4*)(nb + 10240 + (tid + 512) * 16)    = w1v;
        if (tid < 256) *(int4*)(nb + 10240 + (tid + 1024) * 16) = w2v;
    }
    __syncthreads();

    // ---- GEMM1 main loop, 32 k-steps of 32
    for (int kt = 0; kt < 32; ++kt) {
        const char* bb = smem + (kt & 1) * AW_BUF;
        float4 a_nxt; int4 w_nxt0, w_nxt1, w_nxt2;
        const bool more = (kt < 31);
        if (more) {
            a_nxt = *(const float4*)&A[a_gbase + (size_t)(kt + 1) * 32];
            const int4* wb = w1blob + (kt + 1) * (W1BLOB_TILE / 16);
            w_nxt0 = wb[tid]; w_nxt1 = wb[tid + 512];
            if (tid < 256) w_nxt2 = wb[tid + 1024];
        }
        v8h ah0 = *(const v8h*)(bb + aoff0);
        v8h ah1 = *(const v8h*)(bb + aoff1);
        v8h al0 = *(const v8h*)(bb + 5120 + aoff0);
        v8h al1 = *(const v8h*)(bb + 5120 + aoff1);
        v8h wh0 = *(const v8h*)(bb + woff0);
        v8h wh1 = *(const v8h*)(bb + woff1);
        v8h wl0 = *(const v8h*)(bb + 10240 + woff0);
        v8h wl1 = *(const v8h*)(bb + 10240 + woff1);

        acc1[0][0] = MFMA16(ah0, wh0, acc1[0][0]);
        acc1[0][1] = MFMA16(ah0, wh1, acc1[0][1]);
        acc1[1][0] = MFMA16(ah1, wh0, acc1[1][0]);
        acc1[1][1] = MFMA16(ah1, wh1, acc1[1][1]);
        acc2[0][0] = MFMA16(ah0, wl0, acc2[0][0]);
        acc2[0][0] = MFMA16(al0, wh0, acc2[0][0]);
        acc2[0][1] = MFMA16(ah0, wl1, acc2[0][1]);
        acc2[0][1] = MFMA16(al0, wh1, acc2[0][1]);
        acc2[1][0] = MFMA16(ah1, wl0, acc2[1][0]);
        acc2[1][0] = MFMA16(al1, wh0, acc2[1][0]);
        acc2[1][1] = MFMA16(ah1, wl1, acc2[1][1]);
        acc2[1][1] = MFMA16(al1, wh1, acc2[1][1]);

        if (more) {
            char* nb = smem + ((kt + 1) & 1) * AW_BUF;
            AU uh, ul;
            float a4[4] = {a_nxt.x, a_nxt.y, a_nxt.z, a_nxt.w};
            #pragma unroll
            for (int e = 0; e < 4; ++e) {
                _Float16 hh = (_Float16)a4[e];
                uh.h[e] = hh; ul.h[e] = (_Float16)((a4[e] - (float)hh) * 4096.f);
            }
            *(int2*)(nb + arow * 80 + aseg * 8)        = uh.v;
            *(int2*)(nb + 5120 + arow * 80 + aseg * 8) = ul.v;
            *(int4*)(nb + 10240 + tid * 16)            = w_nxt0;
            *(int4*)(nb + 10240 + (tid + 512) * 16)    = w_nxt1;
            if (tid < 256) *(int4*)(nb + 10240 + (tid + 1024) * 16) = w_nxt2;
        }
        __syncthreads();
    }

    // ---- GELU epilogue -> H (fp16 split) into LDS
    {
        float b1v[2];
        #pragma unroll
        for (int ni = 0; ni < 2; ++ni) b1v[ni] = b1[32 * np + 16 * ni + ln15];
        #pragma unroll
        for (int mi = 0; mi < 2; ++mi)
            #pragma unroll
            for (int ni = 0; ni < 2; ++ni)
                #pragma unroll
                for (int r = 0; r < 4; ++r) {
                    float y = acc1[mi][ni][r] + acc2[mi][ni][r] * (1.f / 4096.f) + b1v[ni];
                    float h = 0.5f * y * (1.f + erff(y * 0.70710678118654752f));
                    _Float16 hh = (_Float16)h;
                    _Float16 hl = (_Float16)((h - (float)hh) * 4096.f);
                    int row = 32 * mp + 16 * mi + 4 * q + r;
                    int col = 32 * np + 16 * ni + ln15;
                    *(_Float16*)(smem + HH_OFF + row * 272 + col * 2) = hh;
                    *(_Float16*)(smem + HL_OFF + row * 272 + col * 2) = hl;
                }
    }
    __syncthreads();

    // ---- GEMM2: C2[64][256] = H[64][128] @ W2, fp16-split, 4 k-steps of 32
    v4f c1[2][4], c2[2][4];
    #pragma unroll
    for (int i = 0; i < 2; ++i)
        #pragma unroll
        for (int j = 0; j < 4; ++j) {
            c1[i][j] = (v4f){0.f, 0.f, 0.f, 0.f};
            c2[i][j] = (v4f){0.f, 0.f, 0.f, 0.f};
        }
    const int hoff0 = (32 * mp + ln15) * 272 + q * 16;
    const int hoff1 = hoff0 + 16 * 272;

    for (int ks = 0; ks < 4; ++ks) {
        const int4* w2b = (const int4*)(blobs + W2BLOB_BASE + ks * W2BLOB_TILE);
        #pragma unroll
        for (int i = 0; i < 5; ++i)
            *(int4*)(smem + (tid + 512 * i) * 16) = w2b[tid + 512 * i];
        __syncthreads();

        v8h hh0 = *(const v8h*)(smem + HH_OFF + hoff0 + ks * 64);
        v8h hh1 = *(const v8h*)(smem + HH_OFF + hoff1 + ks * 64);
        v8h hl0 = *(const v8h*)(smem + HL_OFF + hoff0 + ks * 64);
        v8h hl1 = *(const v8h*)(smem + HL_OFF + hoff1 + ks * 64);
        #pragma unroll
        for (int ni = 0; ni < 4; ++ni) {
            int wo = (64 * np + 16 * ni + ln15) * 80 + q * 16;
            v8h w2h = *(const v8h*)(smem + wo);
            v8h w2l = *(const v8h*)(smem + 20480 + wo);
            c1[0][ni] = MFMA16(hh0, w2h, c1[0][ni]);
            c2[0][ni] = MFMA16(hh0, w2l, c2[0][ni]);
            c2[0][ni] = MFMA16(hl0, w2h, c2[0][ni]);
            c1[1][ni] = MFMA16(hh1, w2h, c1[1][ni]);
            c2[1][ni] = MFMA16(hh1, w2l, c2[1][ni]);
            c2[1][ni] = MFMA16(hl1, w2h, c2[1][ni]);
        }
        __syncthreads();
    }

    // ---- theta -> LDS (buf1)
    #pragma unroll
    for (int i = 0; i < 8; ++i) {
        int j = tid + 512 * i;
        int row = j >> 6, c4 = (j & 63) << 2;
        *(float4*)(smem + TH_OFF + row * 1040 + c4 * 4) =
            *(const float4*)&theta[(size_t)(m0 + row) * HNB + c4];
    }
    __syncthreads();

    // ---- u-transform: z = pi*tanh(y2), wrapped residual, u = K*nu -> LDS buf2
    {
        float Kv[4], b2v[4];
        #pragma unroll
        for (int ni = 0; ni < 4; ++ni) {
            int c = 64 * np + 16 * ni + ln15;
            float Pi = expf(logPi[c]);
            float Rr = expf(logR[c]);
            Kv[ni]  = Pi / fmaxf(Pi + Rr, 1e-8f);
            b2v[ni] = b2[c];
        }
        #pragma unroll
        for (int mi = 0; mi < 2; ++mi)
            #pragma unroll
            for (int ni = 0; ni < 4; ++ni)
                #pragma unroll
                for (int r = 0; r < 4; ++r) {
                    float y2 = c1[mi][ni][r] + c2[mi][ni][r] * (1.f / 4096.f) + b2v[ni];
                    float z  = 3.14159265358979323846f * tanhf(y2);
                    int row = 32 * mp + 16 * mi + 4 * q + r;
                    int col = 64 * np + 16 * ni + ln15;
                    float th = *(const float*)(smem + TH_OFF + row * 1040 + col * 4);
                    float diff = z - th;
                    float kq = rintf(diff * 0.15915494309189533577f);
                    float nu = (float)((double)diff - (double)kq * 6.283185307179586476925286766559);
                    *(float*)(smem + U_OFF + row * 1040 + col * 4) = Kv[ni] * nu;
                }
    }
    __syncthreads();

    // ---- in-block local scan over 64 rows; S = theta + d_loc overwrites buf1
    if (tid < 256) {
        const int c = tid;
        float Pi = expf(logPi[c]);
        float Rr = expf(logR[c]);
        float alpha = 1.f - Pi / fmaxf(Pi + Rr, 1e-8f);
        float d = 0.f;
        #pragma unroll
        for (int g = 0; g < 8; ++g) {
            float uv[8], tv[8];
            #pragma unroll
            for (int j = 0; j < 8; ++j)
                uv[j] = *(const float*)(smem + U_OFF + (g * 8 + j) * 1040 + c * 4);
            #pragma unroll
            for (int j = 0; j < 8; ++j) {
                d = fmaf(alpha, d, uv[j]);
                tv[j] = *(const float*)(smem + TH_OFF + (g * 8 + j) * 1040 + c * 4) + d;
            }
            #pragma unroll
            for (int j = 0; j < 8; ++j)
                *(float*)(smem + TH_OFF + (g * 8 + j) * 1040 + c * 4) = tv[j];
        }
        carry[(size_t)blk * 16384 + c] = d;   // chunk-terminal local value
    }
    __syncthreads();

    // ---- coalesced S store
    #pragma unroll
    for (int i = 0; i < 8; ++i) {
        int j = tid + 512 * i;
        int row = j >> 6, c4 = (j & 63) << 2;
        *(float4*)&out0[(size_t)(m0 + row) * HNB + c4] =
            *(const float4*)(smem + TH_OFF + row * 1040 + c4 * 4);
    }
}

// ---------------------------------------------------------------------------
// K2: exclusive scan of chunk carries (factor alpha^64); replicate incoming D
//     into rows {0,16,32,48} of each chunk's slot so K3 can run 4 blocks/chunk.
// ---------------------------------------------------------------------------
__global__ __launch_bounds__(256) void k_cscan(
    const float* __restrict__ logPi,
    const float* __restrict__ logR,
    float* __restrict__ carry)
{
    const int c = threadIdx.x;
    const int b = blockIdx.x;
    float Pi = expf(logPi[c]);
    float Rr = expf(logR[c]);
    float alpha = 1.f - Pi / fmaxf(Pi + Rr, 1e-8f);
    float Apow = alpha;
    #pragma unroll
    for (int i = 0; i < 6; ++i) Apow = Apow * Apow;   // alpha^64
    float cv[NCH];
    #pragma unroll
    for (int s = 0; s < NCH; ++s)
        cv[s] = carry[((size_t)b * NCH + s) * 16384 + c];
    float D = 0.f;
    #pragma unroll
    for (int s = 0; s < NCH; ++s) {
        float t = cv[s];
        size_t base = ((size_t)b * NCH + s) * 16384;
        carry[base + c]            = D;
        carry[base + 16 * 256 + c] = D;
        carry[base + 32 * 256 + c] = D;
        carry[base + 48 * 256 + c] = D;
        D = fmaf(Apow, D, t);
    }
}

// ---------------------------------------------------------------------------
// K3: out0 += alpha^(i+1)*D  (global carry propagation) + broadcast fills.
//     grid 1024: block = (chunk, quarter of 16 rows). Reads its D from a slot
//     inside its own fill range (column-exclusive, read-before-write).
// ---------------------------------------------------------------------------
__global__ __launch_bounds__(256) void k_apply_fill(
    const float* __restrict__ logPi,
    const float* __restrict__ logR,
    float* __restrict__ out0, float* __restrict__ out1,
    float* __restrict__ out2, float* __restrict__ out3)
{
    const int blk = blockIdx.x;
    const int chunk = blk >> 2, qt = blk & 3;
    const int c = threadIdx.x;
    float Pi = expf(logPi[c]);
    float Rr = expf(logR[c]);
    float Kc = Pi / fmaxf(Pi + Rr, 1e-8f);
    float alpha = 1.f - Kc;
    const size_t base = (size_t)chunk * 16384 + (size_t)qt * 16 * 256 + c;
    float D = out3[base];                    // replicated incoming carry
    float w;
    if (qt == 0) w = alpha * D;
    else         w = D * exp2f(__log2f(alpha) * (float)(16 * qt + 1));
    #pragma unroll 4
    for (int i = 0; i < 16; ++i) {
        size_t idx = base + (size_t)i * 256;
        float s = out0[idx];
        out0[idx] = s + w;
        out1[idx] = Pi;
        out2[idx] = Kc;
        out3[idx] = Rr;
        w *= alpha;
    }
}

extern "C" void kernel_launch(void* const* d_in, const int* in_sizes, int n_in,
                              void* d_out, int out_size, void* d_ws, size_t ws_size,
                              hipStream_t stream) {
    const float* theta   = (const float*)d_in[0];
    const float* content = (const float*)d_in[1];
    const float* W1      = (const float*)d_in[2];
    const float* b1      = (const float*)d_in[3];
    const float* W2      = (const float*)d_in[4];
    const float* b2      = (const float*)d_in[5];
    const float* logPi   = (const float*)d_in[6];
    const float* logR    = (const float*)d_in[7];

    float* out  = (float*)d_out;
    float* out0 = out;
    float* out1 = out + (size_t)MTOT * HNB;
    float* out2 = out + (size_t)2 * MTOT * HNB;
    float* out3 = out + (size_t)3 * MTOT * HNB;
    char*  blobs = (char*)out1;   // weight blobs live here until K3 fills out1

    hipLaunchKernelGGL(k_prep, dim3(36), dim3(256), 0, stream, W1, W2, blobs);
    hipLaunchKernelGGL(k_mega, dim3(MTOT / 64), dim3(512), SMEM_SZ, stream,
                       content, theta, b1, b2, logPi, logR, blobs, out0, out3);
    hipLaunchKernelGGL(k_cscan, dim3(NBAT), dim3(256), 0, stream,
                       logPi, logR, out3);
    hipLaunchKernelGGL(k_apply_fill, dim3(NBAT * NCH * 4), dim3(256), 0, stream,
                       logPi, logR, out0, out1, out2, out3);
}